// Round 13
// baseline (247.037 us; speedup 1.0000x reference)
//
#include <hip/hip_runtime.h>
#include <math.h>

#define B_    32
#define C_    384
#define RHO_  25
#define WP_   256
#define PIX_  4096
#define D_    768
#define HID_  40
#define NROWS (B_*C_*RHO_)     // 307200
#define FE_N (RHO_*B_*D_)      // 614400
#define POLARBLK 2048

__device__ __forceinline__ float gelu_exact(float x) {
    return 0.5f * x * (1.f + erff(x * 0.70710678118654752f));
}

// ---------------- K1: bins via LDS atomics + W1 transpose + fe zero ----------------
__global__ __launch_bounds__(256) void prep_kernel(const float* __restrict__ grid,
        const float* __restrict__ W1_0, const float* __restrict__ W1s,
        float* __restrict__ bins, float* __restrict__ W1T, float* __restrict__ fe) {
    __shared__ float lb[PIX_];
    int tid = threadIdx.x;
    if (blockIdx.x < B_ * RHO_) {
        for (int i = tid; i < PIX_ / 4; i += 256) ((float4*)lb)[i] = make_float4(0.f, 0.f, 0.f, 0.f);
        __syncthreads();
        int pt = blockIdx.x * WP_ + tid;                 // (b,rho) block owns its 256 points
        float2 g = ((const float2*)grid)[pt];
        float ix = (g.x + 1.f) * 32.f - 0.5f;
        float iy = (g.y + 1.f) * 32.f - 0.5f;
        float x0f = floorf(ix), y0f = floorf(iy);
        float fx = ix - x0f, fy = iy - y0f;
        int x0 = (int)x0f, y0 = (int)y0f;
        const float s = 1.f / 256.f;
        if ((unsigned)x0 < 64u) {
            if ((unsigned)y0 < 64u)       atomicAdd(&lb[y0 * 64 + x0],       (1.f - fx) * (1.f - fy) * s);
            if ((unsigned)(y0 + 1) < 64u) atomicAdd(&lb[(y0 + 1) * 64 + x0], (1.f - fx) * fy * s);
        }
        if ((unsigned)(x0 + 1) < 64u) {
            if ((unsigned)y0 < 64u)       atomicAdd(&lb[y0 * 64 + x0 + 1],       fx * (1.f - fy) * s);
            if ((unsigned)(y0 + 1) < 64u) atomicAdd(&lb[(y0 + 1) * 64 + x0 + 1], fx * fy * s);
        }
        __syncthreads();
        float4* dst = (float4*)(bins + (size_t)blockIdx.x * PIX_);
        for (int i = tid; i < PIX_ / 4; i += 256) dst[i] = ((float4*)lb)[i];
    } else if (blockIdx.x < B_ * RHO_ + 25) {
        int i = blockIdx.x - B_ * RHO_;                  // head 0..24
        const float* src = (i == 0) ? W1_0 : (W1s + (size_t)(i - 1) * 769 * HID_);
        float* dst = W1T + (size_t)i * HID_ * D_;
        for (int idx = tid; idx < HID_ * D_; idx += 256) {
            int j = idx / D_, c = idx % D_;
            dst[idx] = src[c * HID_ + j];
        }
    } else {
        int z = blockIdx.x - (B_ * RHO_ + 25);           // 0..49, zero fe (cart half accumulated)
        float4* f4 = (float4*)fe;
        int per = FE_N / 4 / 50;                         // 3072 float4 per block
        for (int i = tid; i < per; i += 256)
            f4[z * per + i] = make_float4(0.f, 0.f, 0.f, 0.f);
    }
}

// ---------------- K2: polar mean over width; wave per row, ILP-4 ----------------
__global__ __launch_bounds__(256) void polar_mean_kernel(const float* __restrict__ polar,
                                                         float* __restrict__ fe) {
    int wid = blockIdx.x * 4 + (threadIdx.x >> 6);
    int lane = threadIdx.x & 63;
    const int NW = POLARBLK * 4;                         // 8192 waves
    for (int r0 = wid; r0 < NROWS; r0 += 4 * NW) {
        float s[4];
        #pragma unroll
        for (int k = 0; k < 4; ++k) {
            int r = r0 + k * NW;
            float4 v = (r < NROWS) ? ((const float4*)(polar + (size_t)r * WP_))[lane]
                                   : make_float4(0.f, 0.f, 0.f, 0.f);
            s[k] = v.x + v.y + v.z + v.w;
        }
        #pragma unroll
        for (int m = 32; m >= 1; m >>= 1) {
            #pragma unroll
            for (int k = 0; k < 4; ++k) s[k] += __shfl_xor(s[k], m, 64);
        }
        if (lane == 0) {
            #pragma unroll
            for (int k = 0; k < 4; ++k) {
                int r = r0 + k * NW;
                if (r < NROWS) {
                    int rho = r % RHO_, cch = (r / RHO_) % C_, bb = r / (RHO_ * C_);
                    fe[((size_t)(rho * B_ + bb)) * D_ + cch] = s[k] * (1.f / 256.f);
                }
            }
        }
    }
}

// ---------------- K3: cart GEMM — 4 ch/lane, W in LDS, rho split in two template passes ------
// Block = (b, 128-ch tile, 256-p chunk); 1536 blocks. Stage bins tile (25x256, 25.6 KB) once.
// Lane = j(8 ch) x q(8 p-quads); each lane owns channels c0+{0,32,64,96}. Pass<R0,NR> keeps
// acc[4][NR] fully static (no dynamic indexing -> no scratch); pass 2 re-streams X from L3.
template<int R0, int NR>
__device__ __forceinline__ void cart_pass(const float* __restrict__ xp0, const float* ldsW,
                                          int q, float* __restrict__ feb, int b, int c0) {
    const float* xp[4];
    #pragma unroll
    for (int s = 0; s < 4; ++s) xp[s] = xp0 + (size_t)32 * s * PIX_;

    float acc[4][NR];
    #pragma unroll
    for (int s = 0; s < 4; ++s)
        #pragma unroll
        for (int r = 0; r < NR; ++r) acc[s][r] = 0.f;

    float4 cur[4], nxt[4];
    #pragma unroll
    for (int s = 0; s < 4; ++s) { cur[s] = *(const float4*)(xp[s]); nxt[s] = *(const float4*)(xp[s] + 32); }

    for (int t = 0; t < 8; ++t) {
        float4 xc[4];
        #pragma unroll
        for (int s = 0; s < 4; ++s) { xc[s] = cur[s]; cur[s] = nxt[s]; }
        if (t < 6) {
            #pragma unroll
            for (int s = 0; s < 4; ++s) nxt[s] = *(const float4*)(xp[s] + (t + 2) * 32);
        }
        const float* wb = ldsW + t * 32 + q * 4;
        #pragma unroll
        for (int r = 0; r < NR; ++r) {
            float4 wv = *(const float4*)(wb + ((R0 + r) << 8));   // broadcast, conflict-free
            #pragma unroll
            for (int s = 0; s < 4; ++s)
                acc[s][r] += xc[s].x * wv.x + xc[s].y * wv.y + xc[s].z * wv.z + xc[s].w * wv.w;
        }
    }
    // fold q (lane bits 0..2)
    #pragma unroll
    for (int s = 0; s < 4; ++s)
        #pragma unroll
        for (int r = 0; r < NR; ++r) {
            acc[s][r] += __shfl_xor(acc[s][r], 1, 64);
            acc[s][r] += __shfl_xor(acc[s][r], 2, 64);
            acc[s][r] += __shfl_xor(acc[s][r], 4, 64);
        }
    if (q == 0) {
        #pragma unroll
        for (int r = 0; r < NR; ++r) {
            float* fr = feb + ((size_t)((R0 + r) * B_ + b)) * D_ + 384 + c0;
            #pragma unroll
            for (int s = 0; s < 4; ++s) atomicAdd(fr + 32 * s, acc[s][r]);
        }
    }
}

__global__ __launch_bounds__(256) void cart_kernel(const float* __restrict__ cart,
        const float* __restrict__ bins, float* __restrict__ fe) {
    __shared__ float ldsW[6400];                         // 25 rho x 256 p
    int tid = threadIdx.x;
    int bid = blockIdx.x;                                // 0..1535
    int b   = bid / 48;
    int rem = bid % 48;
    int ct  = rem >> 4;
    int pc  = rem & 15;

    // stage W tile: 25 x 256 floats, coalesced
    {
        const float4* binb4 = (const float4*)(bins + (size_t)b * RHO_ * PIX_ + pc * 256);
        float4* lw4 = (float4*)ldsW;
        #pragma unroll 2
        for (int i = tid; i < 1600; i += 256) {
            int r = i >> 6, e = i & 63;
            lw4[(r << 6) + e] = binb4[(size_t)r * 1024 + e];
        }
    }
    __syncthreads();                                     // the only barrier

    int w = tid >> 6, lane = tid & 63;
    int j = lane >> 3, q = lane & 7;
    int c0 = ct * 128 + w * 8 + j;
    const float* xp0 = cart + ((size_t)b * C_ + c0) * PIX_ + pc * 256 + q * 4;

    cart_pass<0, 13>(xp0, ldsW, q, fe, b, c0);
    cart_pass<13, 12>(xp0, ldsW, q, fe, b, c0);          // X re-read hits L3
}

// ---------------- K4: G[i][b][j] = fe[i][b][:] @ W1 + b1 ; wave per (i,b,j-half) ----------------
__global__ __launch_bounds__(256) void mlp_pre_kernel(const float* __restrict__ fe,
        const float* __restrict__ W1T, const float* __restrict__ b1_0,
        const float* __restrict__ b1s, float* __restrict__ G) {
    int lane = threadIdx.x & 63;
    int trip = blockIdx.x * 4 + (threadIdx.x >> 6);      // 0..1599 = (i,b,jh)
    int jh = trip & 1;
    int pair = trip >> 1;
    int i = pair >> 5, b = pair & 31;
    const float4* f4p = (const float4*)(fe + (size_t)(i * B_ + b) * D_);
    float4 f0 = f4p[lane], f1 = f4p[lane + 64], f2 = f4p[lane + 128];
    int j0 = jh * 20;
    #pragma unroll 2
    for (int j = j0; j < j0 + 20; ++j) {
        const float4* w4p = (const float4*)(W1T + ((size_t)i * HID_ + j) * D_);
        float4 w0 = w4p[lane], w1 = w4p[lane + 64], w2 = w4p[lane + 128];
        float s = f0.x*w0.x + f0.y*w0.y + f0.z*w0.z + f0.w*w0.w
                + f1.x*w1.x + f1.y*w1.y + f1.z*w1.z + f1.w*w1.w
                + f2.x*w2.x + f2.y*w2.y + f2.z*w2.z + f2.w*w2.w;
        #pragma unroll
        for (int m = 32; m >= 1; m >>= 1) s += __shfl_xor(s, m, 64);
        if (lane == 0) {
            float bias = (i == 0) ? b1_0[j] : b1s[(i - 1) * HID_ + j];
            G[(size_t)(i * B_ + b) * HID_ + j] = s + bias;
        }
    }
}

// ---------------- K5: sequential heads, register-resident, wave-synchronous ----------------
__global__ __launch_bounds__(64) void mlp_seq_kernel(const float* __restrict__ G,
        const float* __restrict__ W1s, const float* __restrict__ W2_0,
        const float* __restrict__ b2_0, const float* __restrict__ W2s,
        const float* __restrict__ b2s, float* __restrict__ out) {
    int lane = threadIdx.x;
    int j2 = lane & 31, b = blockIdx.x * 2 + (lane >> 5);
    bool hi = (j2 < 8);
    float g1[25], g2[25], wl1[25], wl2[25], w2a[25], w2b[25], bsc[25];
    #pragma unroll
    for (int i = 0; i < 25; ++i) {
        g1[i] = G[(size_t)(i * B_ + b) * HID_ + j2];
        g2[i] = hi ? G[(size_t)(i * B_ + b) * HID_ + 32 + j2] : 0.f;
    }
    wl1[0] = 0.f; wl2[0] = 0.f;
    w2a[0] = W2_0[j2]; w2b[0] = hi ? W2_0[32 + j2] : 0.f; bsc[0] = b2_0[0];
    #pragma unroll
    for (int i = 1; i < 25; ++i) {
        size_t base = ((size_t)(i - 1) * 769 + 768) * HID_;   // recurrent row of W1
        wl1[i] = W1s[base + j2];
        wl2[i] = hi ? W1s[base + 32 + j2] : 0.f;
        w2a[i] = W2s[(i - 1) * HID_ + j2];
        w2b[i] = hi ? W2s[(i - 1) * HID_ + 32 + j2] : 0.f;
        bsc[i] = b2s[i - 1];
    }
    float op = 0.f;
    #pragma unroll
    for (int i = 0; i < 25; ++i) {
        float x1 = g1[i] + op * wl1[i];
        float x2 = g2[i] + op * wl2[i];
        float p = gelu_exact(x1) * w2a[i] + gelu_exact(x2) * w2b[i];
        #pragma unroll
        for (int m = 16; m >= 1; m >>= 1) p += __shfl_xor(p, m, 64);   // stays within 32-lane group
        float o = p + bsc[i];
        op = o;
        if (j2 == 0) out[b * 25 + i] = fminf(fmaxf(o, 0.f), 3.14159265358979323846f);
    }
}

extern "C" void kernel_launch(void* const* d_in, const int* in_sizes, int n_in,
                              void* d_out, int out_size, void* d_ws, size_t ws_size,
                              hipStream_t stream) {
    const float* polar = (const float*)d_in[0];
    const float* cart  = (const float*)d_in[1];
    const float* grid  = (const float*)d_in[2];
    const float* W1_0  = (const float*)d_in[3];
    const float* b1_0  = (const float*)d_in[4];
    const float* W2_0  = (const float*)d_in[5];
    const float* b2_0  = (const float*)d_in[6];
    const float* W1s   = (const float*)d_in[7];
    const float* b1s   = (const float*)d_in[8];
    const float* W2s   = (const float*)d_in[9];
    const float* b2s   = (const float*)d_in[10];
    float* out = (float*)d_out;

    // ws layout (floats): bins[800*4096] | fe | G | W1T
    float* bins = (float*)d_ws;
    float* fe   = bins + (size_t)B_ * RHO_ * PIX_;
    float* G    = fe + (size_t)FE_N;
    float* W1T  = G + (size_t)RHO_ * B_ * HID_;

    prep_kernel<<<B_ * RHO_ + 25 + 50, 256, 0, stream>>>(grid, W1_0, W1s, bins, W1T, fe);
    polar_mean_kernel<<<POLARBLK, 256, 0, stream>>>(polar, fe);
    cart_kernel<<<B_ * 3 * 16, 256, 0, stream>>>(cart, bins, fe);
    mlp_pre_kernel<<<(RHO_ * B_ * 2) / 4, 256, 0, stream>>>(fe, W1T, b1_0, b1s, G);
    mlp_seq_kernel<<<B_ / 2, 64, 0, stream>>>(G, W1s, W2_0, b2_0, W2s, b2s, out);
}

// Round 14
// 222.634 us; speedup vs baseline: 1.1096x; 1.1096x over previous
//
#include <hip/hip_runtime.h>
#include <math.h>

#define B_    32
#define C_    384
#define RHO_  25
#define WP_   256
#define PIX_  4096
#define D_    768
#define HID_  40
#define NROWS (B_*C_*RHO_)     // 307200
#define FE_N (RHO_*B_*D_)      // 614400
#define POLARBLK 2048

__device__ __forceinline__ float gelu_exact(float x) {
    return 0.5f * x * (1.f + erff(x * 0.70710678118654752f));
}

// ---------------- K1: bins via LDS atomics + W1 transpose + fe zero ----------------
__global__ __launch_bounds__(256) void prep_kernel(const float* __restrict__ grid,
        const float* __restrict__ W1_0, const float* __restrict__ W1s,
        float* __restrict__ bins, float* __restrict__ W1T, float* __restrict__ fe) {
    __shared__ float lb[PIX_];
    int tid = threadIdx.x;
    if (blockIdx.x < B_ * RHO_) {
        for (int i = tid; i < PIX_ / 4; i += 256) ((float4*)lb)[i] = make_float4(0.f, 0.f, 0.f, 0.f);
        __syncthreads();
        int pt = blockIdx.x * WP_ + tid;                 // (b,rho) block owns its 256 points
        float2 g = ((const float2*)grid)[pt];
        float ix = (g.x + 1.f) * 32.f - 0.5f;
        float iy = (g.y + 1.f) * 32.f - 0.5f;
        float x0f = floorf(ix), y0f = floorf(iy);
        float fx = ix - x0f, fy = iy - y0f;
        int x0 = (int)x0f, y0 = (int)y0f;
        const float s = 1.f / 256.f;
        if ((unsigned)x0 < 64u) {
            if ((unsigned)y0 < 64u)       atomicAdd(&lb[y0 * 64 + x0],       (1.f - fx) * (1.f - fy) * s);
            if ((unsigned)(y0 + 1) < 64u) atomicAdd(&lb[(y0 + 1) * 64 + x0], (1.f - fx) * fy * s);
        }
        if ((unsigned)(x0 + 1) < 64u) {
            if ((unsigned)y0 < 64u)       atomicAdd(&lb[y0 * 64 + x0 + 1],       fx * (1.f - fy) * s);
            if ((unsigned)(y0 + 1) < 64u) atomicAdd(&lb[(y0 + 1) * 64 + x0 + 1], fx * fy * s);
        }
        __syncthreads();
        float4* dst = (float4*)(bins + (size_t)blockIdx.x * PIX_);
        for (int i = tid; i < PIX_ / 4; i += 256) dst[i] = ((float4*)lb)[i];
    } else if (blockIdx.x < B_ * RHO_ + 25) {
        int i = blockIdx.x - B_ * RHO_;                  // head 0..24
        const float* src = (i == 0) ? W1_0 : (W1s + (size_t)(i - 1) * 769 * HID_);
        float* dst = W1T + (size_t)i * HID_ * D_;
        for (int idx = tid; idx < HID_ * D_; idx += 256) {
            int j = idx / D_, c = idx % D_;
            dst[idx] = src[c * HID_ + j];
        }
    } else {
        int z = blockIdx.x - (B_ * RHO_ + 25);           // 0..49, zero fe (cart half accumulated)
        float4* f4 = (float4*)fe;
        int per = FE_N / 4 / 50;                         // 3072 float4 per block
        for (int i = tid; i < per; i += 256)
            f4[z * per + i] = make_float4(0.f, 0.f, 0.f, 0.f);
    }
}

// ---------------- K2: polar mean over width; wave per row, ILP-4 ----------------
__global__ __launch_bounds__(256) void polar_mean_kernel(const float* __restrict__ polar,
                                                         float* __restrict__ fe) {
    int wid = blockIdx.x * 4 + (threadIdx.x >> 6);
    int lane = threadIdx.x & 63;
    const int NW = POLARBLK * 4;                         // 8192 waves
    for (int r0 = wid; r0 < NROWS; r0 += 4 * NW) {
        float s[4];
        #pragma unroll
        for (int k = 0; k < 4; ++k) {
            int r = r0 + k * NW;
            float4 v = (r < NROWS) ? ((const float4*)(polar + (size_t)r * WP_))[lane]
                                   : make_float4(0.f, 0.f, 0.f, 0.f);
            s[k] = v.x + v.y + v.z + v.w;
        }
        #pragma unroll
        for (int m = 32; m >= 1; m >>= 1) {
            #pragma unroll
            for (int k = 0; k < 4; ++k) s[k] += __shfl_xor(s[k], m, 64);
        }
        if (lane == 0) {
            #pragma unroll
            for (int k = 0; k < 4; ++k) {
                int r = r0 + k * NW;
                if (r < NROWS) {
                    int rho = r % RHO_, cch = (r / RHO_) % C_, bb = r / (RHO_ * C_);
                    fe[((size_t)(rho * B_ + bb)) * D_ + cch] = s[k] * (1.f / 256.f);
                }
            }
        }
    }
}

// ---------------- K3: cart GEMM — 4 ch/lane, single pass, W in LDS ----------------
// Block = (b, 128-ch tile, 256-p chunk); 1536 blocks. Stage bins tile (25x256, 25.6 KB)
// once, one barrier. Lane = j(8 ch) x q(8 p-quads); lane owns channels c0+{0,32,64,96}.
// Per wave t-iter: 25 ds_read_b128 (8 distinct addrs x 8-lane broadcast = conflict-free)
// feed 400 FMAs; X streamed once with 2-deep register lookahead. acc[4][25] all static.
__global__ __launch_bounds__(256) void cart_kernel(const float* __restrict__ cart,
        const float* __restrict__ bins, float* __restrict__ fe) {
    __shared__ float ldsW[6400];                         // 25 rho x 256 p
    int tid = threadIdx.x;
    int bid = blockIdx.x;                                // 0..1535
    int b   = bid / 48;
    int rem = bid % 48;
    int ct  = rem >> 4;
    int pc  = rem & 15;

    // stage W tile: 25 x 256 floats, coalesced
    {
        const float4* binb4 = (const float4*)(bins + (size_t)b * RHO_ * PIX_ + pc * 256);
        float4* lw4 = (float4*)ldsW;
        #pragma unroll 2
        for (int i = tid; i < 1600; i += 256) {
            int r = i >> 6, e = i & 63;
            lw4[(r << 6) + e] = binb4[(size_t)r * 1024 + e];
        }
    }
    __syncthreads();                                     // the only barrier

    int w = tid >> 6, lane = tid & 63;
    int j = lane >> 3, q = lane & 7;
    int c0 = ct * 128 + w * 8 + j;
    const float* xp0 = cart + ((size_t)b * C_ + c0) * PIX_ + pc * 256 + q * 4;

    float acc[4][25];
    #pragma unroll
    for (int s = 0; s < 4; ++s)
        #pragma unroll
        for (int r = 0; r < 25; ++r) acc[s][r] = 0.f;

    float4 cur[4], nxt[4];
    #pragma unroll
    for (int s = 0; s < 4; ++s) {
        cur[s] = *(const float4*)(xp0 + (size_t)32 * s * PIX_);
        nxt[s] = *(const float4*)(xp0 + (size_t)32 * s * PIX_ + 32);
    }
    for (int t = 0; t < 8; ++t) {
        float4 xc[4];
        #pragma unroll
        for (int s = 0; s < 4; ++s) { xc[s] = cur[s]; cur[s] = nxt[s]; }
        if (t < 6) {
            #pragma unroll
            for (int s = 0; s < 4; ++s)
                nxt[s] = *(const float4*)(xp0 + (size_t)32 * s * PIX_ + (t + 2) * 32);
        }
        const float* wb = ldsW + t * 32 + q * 4;
        #pragma unroll
        for (int r = 0; r < 25; ++r) {
            float4 wv = *(const float4*)(wb + (r << 8));   // broadcast, conflict-free
            #pragma unroll
            for (int s = 0; s < 4; ++s)
                acc[s][r] += xc[s].x * wv.x + xc[s].y * wv.y + xc[s].z * wv.z + xc[s].w * wv.w;
        }
    }
    // fold q (lane bits 0..2)
    #pragma unroll
    for (int s = 0; s < 4; ++s)
        #pragma unroll
        for (int r = 0; r < 25; ++r) {
            acc[s][r] += __shfl_xor(acc[s][r], 1, 64);
            acc[s][r] += __shfl_xor(acc[s][r], 2, 64);
            acc[s][r] += __shfl_xor(acc[s][r], 4, 64);
        }
    if (q == 0) {
        #pragma unroll
        for (int r = 0; r < 25; ++r) {
            float* fr = fe + ((size_t)(r * B_ + b)) * D_ + 384 + c0;
            #pragma unroll
            for (int s = 0; s < 4; ++s) atomicAdd(fr + 32 * s, acc[s][r]);
        }
    }
}

// ---------------- K4: G[i][b][j] = fe[i][b][:] @ W1 + b1 ; wave per (i,b,j-half) ----------------
__global__ __launch_bounds__(256) void mlp_pre_kernel(const float* __restrict__ fe,
        const float* __restrict__ W1T, const float* __restrict__ b1_0,
        const float* __restrict__ b1s, float* __restrict__ G) {
    int lane = threadIdx.x & 63;
    int trip = blockIdx.x * 4 + (threadIdx.x >> 6);      // 0..1599 = (i,b,jh)
    int jh = trip & 1;
    int pair = trip >> 1;
    int i = pair >> 5, b = pair & 31;
    const float4* f4p = (const float4*)(fe + (size_t)(i * B_ + b) * D_);
    float4 f0 = f4p[lane], f1 = f4p[lane + 64], f2 = f4p[lane + 128];
    int j0 = jh * 20;
    #pragma unroll 2
    for (int j = j0; j < j0 + 20; ++j) {
        const float4* w4p = (const float4*)(W1T + ((size_t)i * HID_ + j) * D_);
        float4 w0 = w4p[lane], w1 = w4p[lane + 64], w2 = w4p[lane + 128];
        float s = f0.x*w0.x + f0.y*w0.y + f0.z*w0.z + f0.w*w0.w
                + f1.x*w1.x + f1.y*w1.y + f1.z*w1.z + f1.w*w1.w
                + f2.x*w2.x + f2.y*w2.y + f2.z*w2.z + f2.w*w2.w;
        #pragma unroll
        for (int m = 32; m >= 1; m >>= 1) s += __shfl_xor(s, m, 64);
        if (lane == 0) {
            float bias = (i == 0) ? b1_0[j] : b1s[(i - 1) * HID_ + j];
            G[(size_t)(i * B_ + b) * HID_ + j] = s + bias;
        }
    }
}

// ---------------- K5: sequential heads, register-resident, wave-synchronous ----------------
__global__ __launch_bounds__(64) void mlp_seq_kernel(const float* __restrict__ G,
        const float* __restrict__ W1s, const float* __restrict__ W2_0,
        const float* __restrict__ b2_0, const float* __restrict__ W2s,
        const float* __restrict__ b2s, float* __restrict__ out) {
    int lane = threadIdx.x;
    int j2 = lane & 31, b = blockIdx.x * 2 + (lane >> 5);
    bool hi = (j2 < 8);
    float g1[25], g2[25], wl1[25], wl2[25], w2a[25], w2b[25], bsc[25];
    #pragma unroll
    for (int i = 0; i < 25; ++i) {
        g1[i] = G[(size_t)(i * B_ + b) * HID_ + j2];
        g2[i] = hi ? G[(size_t)(i * B_ + b) * HID_ + 32 + j2] : 0.f;
    }
    wl1[0] = 0.f; wl2[0] = 0.f;
    w2a[0] = W2_0[j2]; w2b[0] = hi ? W2_0[32 + j2] : 0.f; bsc[0] = b2_0[0];
    #pragma unroll
    for (int i = 1; i < 25; ++i) {
        size_t base = ((size_t)(i - 1) * 769 + 768) * HID_;   // recurrent row of W1
        wl1[i] = W1s[base + j2];
        wl2[i] = hi ? W1s[base + 32 + j2] : 0.f;
        w2a[i] = W2s[(i - 1) * HID_ + j2];
        w2b[i] = hi ? W2s[(i - 1) * HID_ + 32 + j2] : 0.f;
        bsc[i] = b2s[i - 1];
    }
    float op = 0.f;
    #pragma unroll
    for (int i = 0; i < 25; ++i) {
        float x1 = g1[i] + op * wl1[i];
        float x2 = g2[i] + op * wl2[i];
        float p = gelu_exact(x1) * w2a[i] + gelu_exact(x2) * w2b[i];
        #pragma unroll
        for (int m = 16; m >= 1; m >>= 1) p += __shfl_xor(p, m, 64);   // stays within 32-lane group
        float o = p + bsc[i];
        op = o;
        if (j2 == 0) out[b * 25 + i] = fminf(fmaxf(o, 0.f), 3.14159265358979323846f);
    }
}

extern "C" void kernel_launch(void* const* d_in, const int* in_sizes, int n_in,
                              void* d_out, int out_size, void* d_ws, size_t ws_size,
                              hipStream_t stream) {
    const float* polar = (const float*)d_in[0];
    const float* cart  = (const float*)d_in[1];
    const float* grid  = (const float*)d_in[2];
    const float* W1_0  = (const float*)d_in[3];
    const float* b1_0  = (const float*)d_in[4];
    const float* W2_0  = (const float*)d_in[5];
    const float* b2_0  = (const float*)d_in[6];
    const float* W1s   = (const float*)d_in[7];
    const float* b1s   = (const float*)d_in[8];
    const float* W2s   = (const float*)d_in[9];
    const float* b2s   = (const float*)d_in[10];
    float* out = (float*)d_out;

    // ws layout (floats): bins[800*4096] | fe | G | W1T
    float* bins = (float*)d_ws;
    float* fe   = bins + (size_t)B_ * RHO_ * PIX_;
    float* G    = fe + (size_t)FE_N;
    float* W1T  = G + (size_t)RHO_ * B_ * HID_;

    prep_kernel<<<B_ * RHO_ + 25 + 50, 256, 0, stream>>>(grid, W1_0, W1s, bins, W1T, fe);
    polar_mean_kernel<<<POLARBLK, 256, 0, stream>>>(polar, fe);
    cart_kernel<<<B_ * 3 * 16, 256, 0, stream>>>(cart, bins, fe);
    mlp_pre_kernel<<<(RHO_ * B_ * 2) / 4, 256, 0, stream>>>(fe, W1T, b1_0, b1s, G);
    mlp_seq_kernel<<<B_ / 2, 64, 0, stream>>>(G, W1s, W2_0, b2_0, W2s, b2s, out);
}

// Round 15
// 205.406 us; speedup vs baseline: 1.2027x; 1.0839x over previous
//
#include <hip/hip_runtime.h>
#include <math.h>

#define B_    32
#define C_    384
#define RHO_  25
#define WP_   256
#define PIX_  4096
#define D_    768
#define HID_  40
#define NROWS (B_*C_*RHO_)     // 307200
#define FE_N (RHO_*B_*D_)      // 614400
#define POLARBLK 2048

__device__ __forceinline__ float gelu_exact(float x) {
    return 0.5f * x * (1.f + erff(x * 0.70710678118654752f));
}

// ---------------- K1: bins via LDS atomics + W1 transpose + fe zero ----------------
__global__ __launch_bounds__(256) void prep_kernel(const float* __restrict__ grid,
        const float* __restrict__ W1_0, const float* __restrict__ W1s,
        float* __restrict__ bins, float* __restrict__ W1T, float* __restrict__ fe) {
    __shared__ float lb[PIX_];
    int tid = threadIdx.x;
    if (blockIdx.x < B_ * RHO_) {
        for (int i = tid; i < PIX_ / 4; i += 256) ((float4*)lb)[i] = make_float4(0.f, 0.f, 0.f, 0.f);
        __syncthreads();
        int pt = blockIdx.x * WP_ + tid;                 // (b,rho) block owns its 256 points
        float2 g = ((const float2*)grid)[pt];
        float ix = (g.x + 1.f) * 32.f - 0.5f;
        float iy = (g.y + 1.f) * 32.f - 0.5f;
        float x0f = floorf(ix), y0f = floorf(iy);
        float fx = ix - x0f, fy = iy - y0f;
        int x0 = (int)x0f, y0 = (int)y0f;
        const float s = 1.f / 256.f;
        if ((unsigned)x0 < 64u) {
            if ((unsigned)y0 < 64u)       atomicAdd(&lb[y0 * 64 + x0],       (1.f - fx) * (1.f - fy) * s);
            if ((unsigned)(y0 + 1) < 64u) atomicAdd(&lb[(y0 + 1) * 64 + x0], (1.f - fx) * fy * s);
        }
        if ((unsigned)(x0 + 1) < 64u) {
            if ((unsigned)y0 < 64u)       atomicAdd(&lb[y0 * 64 + x0 + 1],       fx * (1.f - fy) * s);
            if ((unsigned)(y0 + 1) < 64u) atomicAdd(&lb[(y0 + 1) * 64 + x0 + 1], fx * fy * s);
        }
        __syncthreads();
        float4* dst = (float4*)(bins + (size_t)blockIdx.x * PIX_);
        for (int i = tid; i < PIX_ / 4; i += 256) dst[i] = ((float4*)lb)[i];
    } else if (blockIdx.x < B_ * RHO_ + 25) {
        int i = blockIdx.x - B_ * RHO_;                  // head 0..24
        const float* src = (i == 0) ? W1_0 : (W1s + (size_t)(i - 1) * 769 * HID_);
        float* dst = W1T + (size_t)i * HID_ * D_;
        for (int idx = tid; idx < HID_ * D_; idx += 256) {
            int j = idx / D_, c = idx % D_;
            dst[idx] = src[c * HID_ + j];
        }
    } else {
        int z = blockIdx.x - (B_ * RHO_ + 25);           // 0..49, zero fe (cart half accumulated)
        float4* f4 = (float4*)fe;
        int per = FE_N / 4 / 50;                         // 3072 float4 per block
        for (int i = tid; i < per; i += 256)
            f4[z * per + i] = make_float4(0.f, 0.f, 0.f, 0.f);
    }
}

// ---------------- K2: polar mean over width; wave per row, ILP-4 ----------------
__global__ __launch_bounds__(256) void polar_mean_kernel(const float* __restrict__ polar,
                                                         float* __restrict__ fe) {
    int wid = blockIdx.x * 4 + (threadIdx.x >> 6);
    int lane = threadIdx.x & 63;
    const int NW = POLARBLK * 4;                         // 8192 waves
    for (int r0 = wid; r0 < NROWS; r0 += 4 * NW) {
        float s[4];
        #pragma unroll
        for (int k = 0; k < 4; ++k) {
            int r = r0 + k * NW;
            float4 v = (r < NROWS) ? ((const float4*)(polar + (size_t)r * WP_))[lane]
                                   : make_float4(0.f, 0.f, 0.f, 0.f);
            s[k] = v.x + v.y + v.z + v.w;
        }
        #pragma unroll
        for (int m = 32; m >= 1; m >>= 1) {
            #pragma unroll
            for (int k = 0; k < 4; ++k) s[k] += __shfl_xor(s[k], m, 64);
        }
        if (lane == 0) {
            #pragma unroll
            for (int k = 0; k < 4; ++k) {
                int r = r0 + k * NW;
                if (r < NROWS) {
                    int rho = r % RHO_, cch = (r / RHO_) % C_, bb = r / (RHO_ * C_);
                    fe[((size_t)(rho * B_ + bb)) * D_ + cch] = s[k] * (1.f / 256.f);
                }
            }
        }
    }
}

// ---------------- K3: cart GEMM — 2 ch/lane, single pass, W in LDS ----------------
// Block = (b, 64-ch tile, 256-p chunk); 3072 blocks. Stage bins tile (25x256, 25.6 KB)
// once, one barrier. Lane = j(8 ch) x q(8 p-quads); lane owns channels c0, c0+32.
// Per wave t-iter: 25 ds_read_b128 (8 distinct addrs x 8-lane broadcast, conflict-free)
// feed 200 FMAs; X streamed once with 2-deep register lookahead. acc[2][25] ~ 110 VGPR.
__global__ __launch_bounds__(256) void cart_kernel(const float* __restrict__ cart,
        const float* __restrict__ bins, float* __restrict__ fe) {
    __shared__ float ldsW[6400];                         // 25 rho x 256 p
    int tid = threadIdx.x;
    int bid = blockIdx.x;                                // 0..3071
    int b   = bid / 96;
    int rem = bid % 96;
    int ct  = rem >> 4;
    int pc  = rem & 15;

    // stage W tile: 25 x 256 floats, coalesced
    {
        const float4* binb4 = (const float4*)(bins + (size_t)b * RHO_ * PIX_ + pc * 256);
        float4* lw4 = (float4*)ldsW;
        #pragma unroll 2
        for (int i = tid; i < 1600; i += 256) {
            int r = i >> 6, e = i & 63;
            lw4[(r << 6) + e] = binb4[(size_t)r * 1024 + e];
        }
    }
    __syncthreads();                                     // the only barrier

    int w = tid >> 6, lane = tid & 63;
    int j = lane >> 3, q = lane & 7;
    int c0 = ct * 64 + w * 8 + j;                        // this lane's channels: c0, c0+32
    const float* xp0 = cart + ((size_t)b * C_ + c0) * PIX_ + pc * 256 + q * 4;
    const float* xp1 = xp0 + (size_t)32 * PIX_;

    float acc0[25], acc1[25];
    #pragma unroll
    for (int r = 0; r < 25; ++r) { acc0[r] = 0.f; acc1[r] = 0.f; }

    float4 a0 = *(const float4*)(xp0);
    float4 a1 = *(const float4*)(xp0 + 32);
    float4 b0 = *(const float4*)(xp1);
    float4 b1 = *(const float4*)(xp1 + 32);
    for (int t = 0; t < 8; ++t) {
        float4 xa = a0, xb = b0;
        a0 = a1; b0 = b1;
        if (t < 6) {
            a1 = *(const float4*)(xp0 + (t + 2) * 32);
            b1 = *(const float4*)(xp1 + (t + 2) * 32);
        }
        const float* wb = ldsW + t * 32 + q * 4;
        #pragma unroll
        for (int r = 0; r < 25; ++r) {
            float4 wv = *(const float4*)(wb + (r << 8));   // broadcast, conflict-free
            acc0[r] += xa.x * wv.x + xa.y * wv.y + xa.z * wv.z + xa.w * wv.w;
            acc1[r] += xb.x * wv.x + xb.y * wv.y + xb.z * wv.z + xb.w * wv.w;
        }
    }
    // fold q (lane bits 0..2)
    #pragma unroll
    for (int r = 0; r < 25; ++r) {
        acc0[r] += __shfl_xor(acc0[r], 1, 64);
        acc0[r] += __shfl_xor(acc0[r], 2, 64);
        acc0[r] += __shfl_xor(acc0[r], 4, 64);
        acc1[r] += __shfl_xor(acc1[r], 1, 64);
        acc1[r] += __shfl_xor(acc1[r], 2, 64);
        acc1[r] += __shfl_xor(acc1[r], 4, 64);
    }
    if (q == 0) {
        #pragma unroll
        for (int r = 0; r < 25; ++r) {
            float* fr = fe + ((size_t)(r * B_ + b)) * D_ + 384;
            atomicAdd(fr + c0,      acc0[r]);
            atomicAdd(fr + c0 + 32, acc1[r]);
        }
    }
}

// ---------------- K4: G[i][b][j] = fe[i][b][:] @ W1 + b1 ; wave per (i,b,j-half) ----------------
__global__ __launch_bounds__(256) void mlp_pre_kernel(const float* __restrict__ fe,
        const float* __restrict__ W1T, const float* __restrict__ b1_0,
        const float* __restrict__ b1s, float* __restrict__ G) {
    int lane = threadIdx.x & 63;
    int trip = blockIdx.x * 4 + (threadIdx.x >> 6);      // 0..1599 = (i,b,jh)
    int jh = trip & 1;
    int pair = trip >> 1;
    int i = pair >> 5, b = pair & 31;
    const float4* f4p = (const float4*)(fe + (size_t)(i * B_ + b) * D_);
    float4 f0 = f4p[lane], f1 = f4p[lane + 64], f2 = f4p[lane + 128];
    int j0 = jh * 20;
    #pragma unroll 2
    for (int j = j0; j < j0 + 20; ++j) {
        const float4* w4p = (const float4*)(W1T + ((size_t)i * HID_ + j) * D_);
        float4 w0 = w4p[lane], w1 = w4p[lane + 64], w2 = w4p[lane + 128];
        float s = f0.x*w0.x + f0.y*w0.y + f0.z*w0.z + f0.w*w0.w
                + f1.x*w1.x + f1.y*w1.y + f1.z*w1.z + f1.w*w1.w
                + f2.x*w2.x + f2.y*w2.y + f2.z*w2.z + f2.w*w2.w;
        #pragma unroll
        for (int m = 32; m >= 1; m >>= 1) s += __shfl_xor(s, m, 64);
        if (lane == 0) {
            float bias = (i == 0) ? b1_0[j] : b1s[(i - 1) * HID_ + j];
            G[(size_t)(i * B_ + b) * HID_ + j] = s + bias;
        }
    }
}

// ---------------- K5: sequential heads, register-resident, wave-synchronous ----------------
__global__ __launch_bounds__(64) void mlp_seq_kernel(const float* __restrict__ G,
        const float* __restrict__ W1s, const float* __restrict__ W2_0,
        const float* __restrict__ b2_0, const float* __restrict__ W2s,
        const float* __restrict__ b2s, float* __restrict__ out) {
    int lane = threadIdx.x;
    int j2 = lane & 31, b = blockIdx.x * 2 + (lane >> 5);
    bool hi = (j2 < 8);
    float g1[25], g2[25], wl1[25], wl2[25], w2a[25], w2b[25], bsc[25];
    #pragma unroll
    for (int i = 0; i < 25; ++i) {
        g1[i] = G[(size_t)(i * B_ + b) * HID_ + j2];
        g2[i] = hi ? G[(size_t)(i * B_ + b) * HID_ + 32 + j2] : 0.f;
    }
    wl1[0] = 0.f; wl2[0] = 0.f;
    w2a[0] = W2_0[j2]; w2b[0] = hi ? W2_0[32 + j2] : 0.f; bsc[0] = b2_0[0];
    #pragma unroll
    for (int i = 1; i < 25; ++i) {
        size_t base = ((size_t)(i - 1) * 769 + 768) * HID_;   // recurrent row of W1
        wl1[i] = W1s[base + j2];
        wl2[i] = hi ? W1s[base + 32 + j2] : 0.f;
        w2a[i] = W2s[(i - 1) * HID_ + j2];
        w2b[i] = hi ? W2s[(i - 1) * HID_ + 32 + j2] : 0.f;
        bsc[i] = b2s[i - 1];
    }
    float op = 0.f;
    #pragma unroll
    for (int i = 0; i < 25; ++i) {
        float x1 = g1[i] + op * wl1[i];
        float x2 = g2[i] + op * wl2[i];
        float p = gelu_exact(x1) * w2a[i] + gelu_exact(x2) * w2b[i];
        #pragma unroll
        for (int m = 16; m >= 1; m >>= 1) p += __shfl_xor(p, m, 64);   // stays within 32-lane group
        float o = p + bsc[i];
        op = o;
        if (j2 == 0) out[b * 25 + i] = fminf(fmaxf(o, 0.f), 3.14159265358979323846f);
    }
}

extern "C" void kernel_launch(void* const* d_in, const int* in_sizes, int n_in,
                              void* d_out, int out_size, void* d_ws, size_t ws_size,
                              hipStream_t stream) {
    const float* polar = (const float*)d_in[0];
    const float* cart  = (const float*)d_in[1];
    const float* grid  = (const float*)d_in[2];
    const float* W1_0  = (const float*)d_in[3];
    const float* b1_0  = (const float*)d_in[4];
    const float* W2_0  = (const float*)d_in[5];
    const float* b2_0  = (const float*)d_in[6];
    const float* W1s   = (const float*)d_in[7];
    const float* b1s   = (const float*)d_in[8];
    const float* W2s   = (const float*)d_in[9];
    const float* b2s   = (const float*)d_in[10];
    float* out = (float*)d_out;

    // ws layout (floats): bins[800*4096] | fe | G | W1T
    float* bins = (float*)d_ws;
    float* fe   = bins + (size_t)B_ * RHO_ * PIX_;
    float* G    = fe + (size_t)FE_N;
    float* W1T  = G + (size_t)RHO_ * B_ * HID_;

    prep_kernel<<<B_ * RHO_ + 25 + 50, 256, 0, stream>>>(grid, W1_0, W1s, bins, W1T, fe);
    polar_mean_kernel<<<POLARBLK, 256, 0, stream>>>(polar, fe);
    cart_kernel<<<B_ * 6 * 16, 256, 0, stream>>>(cart, bins, fe);
    mlp_pre_kernel<<<(RHO_ * B_ * 2) / 4, 256, 0, stream>>>(fe, W1T, b1_0, b1s, G);
    mlp_seq_kernel<<<B_ / 2, 64, 0, stream>>>(G, W1s, W2_0, b2_0, W2s, b2s, out);
}

// Round 16
// 190.212 us; speedup vs baseline: 1.2987x; 1.0799x over previous
//
#include <hip/hip_runtime.h>
#include <math.h>

#define B_    32
#define C_    384
#define RHO_  25
#define WP_   256
#define PIX_  4096
#define D_    768
#define HID_  40
#define NROWS (B_*C_*RHO_)     // 307200
#define FE_N (RHO_*B_*D_)      // 614400
#define POLARBLK 2048

__device__ __forceinline__ float gelu_exact(float x) {
    return 0.5f * x * (1.f + erff(x * 0.70710678118654752f));
}

// ---------------- K1: bins via LDS atomics + W1 transpose + fe zero ----------------
__global__ __launch_bounds__(256) void prep_kernel(const float* __restrict__ grid,
        const float* __restrict__ W1_0, const float* __restrict__ W1s,
        float* __restrict__ bins, float* __restrict__ W1T, float* __restrict__ fe) {
    __shared__ float lb[PIX_];
    int tid = threadIdx.x;
    if (blockIdx.x < B_ * RHO_) {
        for (int i = tid; i < PIX_ / 4; i += 256) ((float4*)lb)[i] = make_float4(0.f, 0.f, 0.f, 0.f);
        __syncthreads();
        int pt = blockIdx.x * WP_ + tid;                 // (b,rho) block owns its 256 points
        float2 g = ((const float2*)grid)[pt];
        float ix = (g.x + 1.f) * 32.f - 0.5f;
        float iy = (g.y + 1.f) * 32.f - 0.5f;
        float x0f = floorf(ix), y0f = floorf(iy);
        float fx = ix - x0f, fy = iy - y0f;
        int x0 = (int)x0f, y0 = (int)y0f;
        const float s = 1.f / 256.f;
        if ((unsigned)x0 < 64u) {
            if ((unsigned)y0 < 64u)       atomicAdd(&lb[y0 * 64 + x0],       (1.f - fx) * (1.f - fy) * s);
            if ((unsigned)(y0 + 1) < 64u) atomicAdd(&lb[(y0 + 1) * 64 + x0], (1.f - fx) * fy * s);
        }
        if ((unsigned)(x0 + 1) < 64u) {
            if ((unsigned)y0 < 64u)       atomicAdd(&lb[y0 * 64 + x0 + 1],       fx * (1.f - fy) * s);
            if ((unsigned)(y0 + 1) < 64u) atomicAdd(&lb[(y0 + 1) * 64 + x0 + 1], fx * fy * s);
        }
        __syncthreads();
        float4* dst = (float4*)(bins + (size_t)blockIdx.x * PIX_);
        for (int i = tid; i < PIX_ / 4; i += 256) dst[i] = ((float4*)lb)[i];
    } else if (blockIdx.x < B_ * RHO_ + 25) {
        int i = blockIdx.x - B_ * RHO_;                  // head 0..24
        const float* src = (i == 0) ? W1_0 : (W1s + (size_t)(i - 1) * 769 * HID_);
        float* dst = W1T + (size_t)i * HID_ * D_;
        for (int idx = tid; idx < HID_ * D_; idx += 256) {
            int j = idx / D_, c = idx % D_;
            dst[idx] = src[c * HID_ + j];
        }
    } else {
        int z = blockIdx.x - (B_ * RHO_ + 25);           // 0..49, zero fe (cart half accumulated)
        float4* f4 = (float4*)fe;
        int per = FE_N / 4 / 50;                         // 3072 float4 per block
        for (int i = tid; i < per; i += 256)
            f4[z * per + i] = make_float4(0.f, 0.f, 0.f, 0.f);
    }
}

// ---------------- K2: polar mean over width; wave per row, ILP-4 ----------------
__global__ __launch_bounds__(256) void polar_mean_kernel(const float* __restrict__ polar,
                                                         float* __restrict__ fe) {
    int wid = blockIdx.x * 4 + (threadIdx.x >> 6);
    int lane = threadIdx.x & 63;
    const int NW = POLARBLK * 4;                         // 8192 waves
    for (int r0 = wid; r0 < NROWS; r0 += 4 * NW) {
        float s[4];
        #pragma unroll
        for (int k = 0; k < 4; ++k) {
            int r = r0 + k * NW;
            float4 v = (r < NROWS) ? ((const float4*)(polar + (size_t)r * WP_))[lane]
                                   : make_float4(0.f, 0.f, 0.f, 0.f);
            s[k] = v.x + v.y + v.z + v.w;
        }
        #pragma unroll
        for (int m = 32; m >= 1; m >>= 1) {
            #pragma unroll
            for (int k = 0; k < 4; ++k) s[k] += __shfl_xor(s[k], m, 64);
        }
        if (lane == 0) {
            #pragma unroll
            for (int k = 0; k < 4; ++k) {
                int r = r0 + k * NW;
                if (r < NROWS) {
                    int rho = r % RHO_, cch = (r / RHO_) % C_, bb = r / (RHO_ * C_);
                    fe[((size_t)(rho * B_ + bb)) * D_ + cch] = s[k] * (1.f / 256.f);
                }
            }
        }
    }
}

// ---------------- K3: cart GEMM — 2 ch/lane, 512-p blocks, W restaged, coalesced atomics ----
// Block = (b, 64-ch tile, 512-p group); 1536 blocks = exactly 6/CU (153.6 KB LDS/CU).
// 16 t-iters; W tile (25x256, 25.6 KB) staged at t=0 and t=8; X stream continuous with
// 2-deep lookahead. Epilogue: fold q, stage 25x64 output in LDS, coalesced atomicAdd.
__global__ __launch_bounds__(256) void cart_kernel(const float* __restrict__ cart,
        const float* __restrict__ bins, float* __restrict__ fe) {
    __shared__ float ldsW[6400];                         // 25 rho x 256 p (reused for output)
    int tid = threadIdx.x;
    int bid = blockIdx.x;                                // 0..1535
    int b   = bid / 48;
    int rem = bid % 48;
    int ct  = rem >> 3;                                  // 0..5
    int pg  = rem & 7;                                   // 0..7 (512-p group)

    const float* binb = bins + (size_t)b * RHO_ * PIX_ + pg * 512;
    // stage W for chunk 0
    {
        const float4* b4 = (const float4*)binb;
        #pragma unroll 2
        for (int i = tid; i < 1600; i += 256) {
            int r = i >> 6, e = i & 63;
            ((float4*)ldsW)[(r << 6) + e] = b4[(size_t)r * 1024 + e];
        }
    }
    __syncthreads();

    int w = tid >> 6, lane = tid & 63;
    int j = lane >> 3, q = lane & 7;
    int c0 = ct * 64 + w * 8 + j;                        // this lane's channels: c0, c0+32
    const float* xp0 = cart + ((size_t)b * C_ + c0) * PIX_ + pg * 512 + q * 4;
    const float* xp1 = xp0 + (size_t)32 * PIX_;

    float acc0[25], acc1[25];
    #pragma unroll
    for (int r = 0; r < 25; ++r) { acc0[r] = 0.f; acc1[r] = 0.f; }

    float4 a0 = *(const float4*)(xp0);
    float4 a1 = *(const float4*)(xp0 + 32);
    float4 b0 = *(const float4*)(xp1);
    float4 b1 = *(const float4*)(xp1 + 32);
    for (int t = 0; t < 16; ++t) {
        if (t == 8) {                                    // restage W for chunk 1
            __syncthreads();
            const float4* b4 = (const float4*)(binb + 256);
            #pragma unroll 2
            for (int i = tid; i < 1600; i += 256) {
                int r = i >> 6, e = i & 63;
                ((float4*)ldsW)[(r << 6) + e] = b4[(size_t)r * 1024 + e];
            }
            __syncthreads();
        }
        float4 xa = a0, xb = b0;
        a0 = a1; b0 = b1;
        if (t < 14) {
            a1 = *(const float4*)(xp0 + (t + 2) * 32);   // X continuous across chunk boundary
            b1 = *(const float4*)(xp1 + (t + 2) * 32);
        }
        const float* wb = ldsW + (t & 7) * 32 + q * 4;
        #pragma unroll
        for (int r = 0; r < 25; ++r) {
            float4 wv = *(const float4*)(wb + (r << 8));   // broadcast, conflict-free
            acc0[r] += xa.x * wv.x + xa.y * wv.y + xa.z * wv.z + xa.w * wv.w;
            acc1[r] += xb.x * wv.x + xb.y * wv.y + xb.z * wv.z + xb.w * wv.w;
        }
    }
    // fold q (lane bits 0..2)
    #pragma unroll
    for (int r = 0; r < 25; ++r) {
        acc0[r] += __shfl_xor(acc0[r], 1, 64);
        acc0[r] += __shfl_xor(acc0[r], 2, 64);
        acc0[r] += __shfl_xor(acc0[r], 4, 64);
        acc1[r] += __shfl_xor(acc1[r], 1, 64);
        acc1[r] += __shfl_xor(acc1[r], 2, 64);
        acc1[r] += __shfl_xor(acc1[r], 4, 64);
    }
    __syncthreads();                                     // all waves done reading W
    if (q == 0) {
        #pragma unroll
        for (int r = 0; r < 25; ++r) {
            ldsW[r * 64 + w * 8 + j]      = acc0[r];     // output tile [25][64]
            ldsW[r * 64 + 32 + w * 8 + j] = acc1[r];
        }
    }
    __syncthreads();
    for (int oi = tid; oi < 1600; oi += 256) {           // coalesced atomic adds
        int r = oi >> 6, cc = oi & 63;
        atomicAdd(&fe[((size_t)(r * B_ + b)) * D_ + 384 + ct * 64 + cc], ldsW[oi]);
    }
}

// ---------------- K4: G[i][b][j] = fe[i][b][:] @ W1 + b1 ; wave per (i,b,j-half) ----------------
__global__ __launch_bounds__(256) void mlp_pre_kernel(const float* __restrict__ fe,
        const float* __restrict__ W1T, const float* __restrict__ b1_0,
        const float* __restrict__ b1s, float* __restrict__ G) {
    int lane = threadIdx.x & 63;
    int trip = blockIdx.x * 4 + (threadIdx.x >> 6);      // 0..1599 = (i,b,jh)
    int jh = trip & 1;
    int pair = trip >> 1;
    int i = pair >> 5, b = pair & 31;
    const float4* f4p = (const float4*)(fe + (size_t)(i * B_ + b) * D_);
    float4 f0 = f4p[lane], f1 = f4p[lane + 64], f2 = f4p[lane + 128];
    int j0 = jh * 20;
    #pragma unroll 2
    for (int j = j0; j < j0 + 20; ++j) {
        const float4* w4p = (const float4*)(W1T + ((size_t)i * HID_ + j) * D_);
        float4 w0 = w4p[lane], w1 = w4p[lane + 64], w2 = w4p[lane + 128];
        float s = f0.x*w0.x + f0.y*w0.y + f0.z*w0.z + f0.w*w0.w
                + f1.x*w1.x + f1.y*w1.y + f1.z*w1.z + f1.w*w1.w
                + f2.x*w2.x + f2.y*w2.y + f2.z*w2.z + f2.w*w2.w;
        #pragma unroll
        for (int m = 32; m >= 1; m >>= 1) s += __shfl_xor(s, m, 64);
        if (lane == 0) {
            float bias = (i == 0) ? b1_0[j] : b1s[(i - 1) * HID_ + j];
            G[(size_t)(i * B_ + b) * HID_ + j] = s + bias;
        }
    }
}

// ---------------- K5: sequential heads, register-resident, wave-synchronous ----------------
__global__ __launch_bounds__(64) void mlp_seq_kernel(const float* __restrict__ G,
        const float* __restrict__ W1s, const float* __restrict__ W2_0,
        const float* __restrict__ b2_0, const float* __restrict__ W2s,
        const float* __restrict__ b2s, float* __restrict__ out) {
    int lane = threadIdx.x;
    int j2 = lane & 31, b = blockIdx.x * 2 + (lane >> 5);
    bool hi = (j2 < 8);
    float g1[25], g2[25], wl1[25], wl2[25], w2a[25], w2b[25], bsc[25];
    #pragma unroll
    for (int i = 0; i < 25; ++i) {
        g1[i] = G[(size_t)(i * B_ + b) * HID_ + j2];
        g2[i] = hi ? G[(size_t)(i * B_ + b) * HID_ + 32 + j2] : 0.f;
    }
    wl1[0] = 0.f; wl2[0] = 0.f;
    w2a[0] = W2_0[j2]; w2b[0] = hi ? W2_0[32 + j2] : 0.f; bsc[0] = b2_0[0];
    #pragma unroll
    for (int i = 1; i < 25; ++i) {
        size_t base = ((size_t)(i - 1) * 769 + 768) * HID_;   // recurrent row of W1
        wl1[i] = W1s[base + j2];
        wl2[i] = hi ? W1s[base + 32 + j2] : 0.f;
        w2a[i] = W2s[(i - 1) * HID_ + j2];
        w2b[i] = hi ? W2s[(i - 1) * HID_ + 32 + j2] : 0.f;
        bsc[i] = b2s[i - 1];
    }
    float op = 0.f;
    #pragma unroll
    for (int i = 0; i < 25; ++i) {
        float x1 = g1[i] + op * wl1[i];
        float x2 = g2[i] + op * wl2[i];
        float p = gelu_exact(x1) * w2a[i] + gelu_exact(x2) * w2b[i];
        #pragma unroll
        for (int m = 16; m >= 1; m >>= 1) p += __shfl_xor(p, m, 64);   // stays within 32-lane group
        float o = p + bsc[i];
        op = o;
        if (j2 == 0) out[b * 25 + i] = fminf(fmaxf(o, 0.f), 3.14159265358979323846f);
    }
}

extern "C" void kernel_launch(void* const* d_in, const int* in_sizes, int n_in,
                              void* d_out, int out_size, void* d_ws, size_t ws_size,
                              hipStream_t stream) {
    const float* polar = (const float*)d_in[0];
    const float* cart  = (const float*)d_in[1];
    const float* grid  = (const float*)d_in[2];
    const float* W1_0  = (const float*)d_in[3];
    const float* b1_0  = (const float*)d_in[4];
    const float* W2_0  = (const float*)d_in[5];
    const float* b2_0  = (const float*)d_in[6];
    const float* W1s   = (const float*)d_in[7];
    const float* b1s   = (const float*)d_in[8];
    const float* W2s   = (const float*)d_in[9];
    const float* b2s   = (const float*)d_in[10];
    float* out = (float*)d_out;

    // ws layout (floats): bins[800*4096] | fe | G | W1T
    float* bins = (float*)d_ws;
    float* fe   = bins + (size_t)B_ * RHO_ * PIX_;
    float* G    = fe + (size_t)FE_N;
    float* W1T  = G + (size_t)RHO_ * B_ * HID_;

    prep_kernel<<<B_ * RHO_ + 25 + 50, 256, 0, stream>>>(grid, W1_0, W1s, bins, W1T, fe);
    polar_mean_kernel<<<POLARBLK, 256, 0, stream>>>(polar, fe);
    cart_kernel<<<1536, 256, 0, stream>>>(cart, bins, fe);
    mlp_pre_kernel<<<(RHO_ * B_ * 2) / 4, 256, 0, stream>>>(fe, W1T, b1_0, b1s, G);
    mlp_seq_kernel<<<B_ / 2, 64, 0, stream>>>(G, W1s, W2_0, b2_0, W2s, b2s, out);
}

// Round 17
// 178.978 us; speedup vs baseline: 1.3803x; 1.0628x over previous
//
#include <hip/hip_runtime.h>
#include <math.h>

#define B_    32
#define C_    384
#define RHO_  25
#define WP_   256
#define PIX_  4096
#define D_    768
#define HID_  40
#define NROWS (B_*C_*RHO_)     // 307200
#define FE_N (RHO_*B_*D_)      // 614400
#define POLARBLK 2048

__device__ __forceinline__ float gelu_exact(float x) {
    return 0.5f * x * (1.f + erff(x * 0.70710678118654752f));
}

// ---------------- K1: front — polar mean + bins + W1T + fe-zero (disjoint block roles) ----
// bid < 2048: polar width-mean (8 blocks/CU, BW-critical). 2048..2847: bins via LDS
// atomics. 2848..2872: W1T transpose. 2873..2922: zero fe's cart half [384,768) only
// (polar stores to [0,384) race-free). prep traffic hides under polar's HBM stream.
__global__ __launch_bounds__(256) void front_kernel(const float* __restrict__ polar,
        const float* __restrict__ grid,
        const float* __restrict__ W1_0, const float* __restrict__ W1s,
        float* __restrict__ bins, float* __restrict__ W1T, float* __restrict__ fe) {
    __shared__ float lb[PIX_];
    int tid = threadIdx.x;
    int bid = blockIdx.x;
    if (bid < POLARBLK) {
        // -------- polar role: wave per row, ILP-4 --------
        int wid = bid * 4 + (tid >> 6);
        int lane = tid & 63;
        const int NW = POLARBLK * 4;                     // 8192 waves
        for (int r0 = wid; r0 < NROWS; r0 += 4 * NW) {
            float s[4];
            #pragma unroll
            for (int k = 0; k < 4; ++k) {
                int r = r0 + k * NW;
                float4 v = (r < NROWS) ? ((const float4*)(polar + (size_t)r * WP_))[lane]
                                       : make_float4(0.f, 0.f, 0.f, 0.f);
                s[k] = v.x + v.y + v.z + v.w;
            }
            #pragma unroll
            for (int m = 32; m >= 1; m >>= 1) {
                #pragma unroll
                for (int k = 0; k < 4; ++k) s[k] += __shfl_xor(s[k], m, 64);
            }
            if (lane == 0) {
                #pragma unroll
                for (int k = 0; k < 4; ++k) {
                    int r = r0 + k * NW;
                    if (r < NROWS) {
                        int rho = r % RHO_, cch = (r / RHO_) % C_, bb = r / (RHO_ * C_);
                        fe[((size_t)(rho * B_ + bb)) * D_ + cch] = s[k] * (1.f / 256.f);
                    }
                }
            }
        }
    } else if (bid < POLARBLK + B_ * RHO_) {
        // -------- bins role: per-(b,rho) LDS scatter --------
        int bb = bid - POLARBLK;                         // 0..799
        for (int i = tid; i < PIX_ / 4; i += 256) ((float4*)lb)[i] = make_float4(0.f, 0.f, 0.f, 0.f);
        __syncthreads();
        int pt = bb * WP_ + tid;
        float2 g = ((const float2*)grid)[pt];
        float ix = (g.x + 1.f) * 32.f - 0.5f;
        float iy = (g.y + 1.f) * 32.f - 0.5f;
        float x0f = floorf(ix), y0f = floorf(iy);
        float fx = ix - x0f, fy = iy - y0f;
        int x0 = (int)x0f, y0 = (int)y0f;
        const float s = 1.f / 256.f;
        if ((unsigned)x0 < 64u) {
            if ((unsigned)y0 < 64u)       atomicAdd(&lb[y0 * 64 + x0],       (1.f - fx) * (1.f - fy) * s);
            if ((unsigned)(y0 + 1) < 64u) atomicAdd(&lb[(y0 + 1) * 64 + x0], (1.f - fx) * fy * s);
        }
        if ((unsigned)(x0 + 1) < 64u) {
            if ((unsigned)y0 < 64u)       atomicAdd(&lb[y0 * 64 + x0 + 1],       fx * (1.f - fy) * s);
            if ((unsigned)(y0 + 1) < 64u) atomicAdd(&lb[(y0 + 1) * 64 + x0 + 1], fx * fy * s);
        }
        __syncthreads();
        float4* dst = (float4*)(bins + (size_t)bb * PIX_);
        for (int i = tid; i < PIX_ / 4; i += 256) dst[i] = ((float4*)lb)[i];
    } else if (bid < POLARBLK + B_ * RHO_ + 25) {
        // -------- W1T role --------
        int i = bid - (POLARBLK + B_ * RHO_);            // head 0..24
        const float* src = (i == 0) ? W1_0 : (W1s + (size_t)(i - 1) * 769 * HID_);
        float* dst = W1T + (size_t)i * HID_ * D_;
        for (int idx = tid; idx < HID_ * D_; idx += 256) {
            int j = idx / D_, c = idx % D_;
            dst[idx] = src[c * HID_ + j];
        }
    } else {
        // -------- fe-zero role: cart half only, 16 rows per block --------
        int z = bid - (POLARBLK + B_ * RHO_ + 25);       // 0..49
        for (int i = tid; i < 16 * 96; i += 256) {       // 16 rows x 96 float4
            int row = z * 16 + (i / 96), e = i % 96;
            ((float4*)fe)[(size_t)row * 192 + 96 + e] = make_float4(0.f, 0.f, 0.f, 0.f);
        }
    }
}

// ---------------- K2: cart GEMM — 2 ch/lane, 512-p blocks, W restaged, coalesced atomics ----
// (byte-identical to R16 best) Block = (b, 64-ch tile, 512-p group); 1536 blocks.
__global__ __launch_bounds__(256) void cart_kernel(const float* __restrict__ cart,
        const float* __restrict__ bins, float* __restrict__ fe) {
    __shared__ float ldsW[6400];                         // 25 rho x 256 p (reused for output)
    int tid = threadIdx.x;
    int bid = blockIdx.x;                                // 0..1535
    int b   = bid / 48;
    int rem = bid % 48;
    int ct  = rem >> 3;                                  // 0..5
    int pg  = rem & 7;                                   // 0..7 (512-p group)

    const float* binb = bins + (size_t)b * RHO_ * PIX_ + pg * 512;
    {
        const float4* b4 = (const float4*)binb;
        #pragma unroll 2
        for (int i = tid; i < 1600; i += 256) {
            int r = i >> 6, e = i & 63;
            ((float4*)ldsW)[(r << 6) + e] = b4[(size_t)r * 1024 + e];
        }
    }
    __syncthreads();

    int w = tid >> 6, lane = tid & 63;
    int j = lane >> 3, q = lane & 7;
    int c0 = ct * 64 + w * 8 + j;                        // this lane's channels: c0, c0+32
    const float* xp0 = cart + ((size_t)b * C_ + c0) * PIX_ + pg * 512 + q * 4;
    const float* xp1 = xp0 + (size_t)32 * PIX_;

    float acc0[25], acc1[25];
    #pragma unroll
    for (int r = 0; r < 25; ++r) { acc0[r] = 0.f; acc1[r] = 0.f; }

    float4 a0 = *(const float4*)(xp0);
    float4 a1 = *(const float4*)(xp0 + 32);
    float4 b0 = *(const float4*)(xp1);
    float4 b1 = *(const float4*)(xp1 + 32);
    for (int t = 0; t < 16; ++t) {
        if (t == 8) {                                    // restage W for chunk 1
            __syncthreads();
            const float4* b4 = (const float4*)(binb + 256);
            #pragma unroll 2
            for (int i = tid; i < 1600; i += 256) {
                int r = i >> 6, e = i & 63;
                ((float4*)ldsW)[(r << 6) + e] = b4[(size_t)r * 1024 + e];
            }
            __syncthreads();
        }
        float4 xa = a0, xb = b0;
        a0 = a1; b0 = b1;
        if (t < 14) {
            a1 = *(const float4*)(xp0 + (t + 2) * 32);   // X continuous across chunk boundary
            b1 = *(const float4*)(xp1 + (t + 2) * 32);
        }
        const float* wb = ldsW + (t & 7) * 32 + q * 4;
        #pragma unroll
        for (int r = 0; r < 25; ++r) {
            float4 wv = *(const float4*)(wb + (r << 8));   // broadcast, conflict-free
            acc0[r] += xa.x * wv.x + xa.y * wv.y + xa.z * wv.z + xa.w * wv.w;
            acc1[r] += xb.x * wv.x + xb.y * wv.y + xb.z * wv.z + xb.w * wv.w;
        }
    }
    // fold q (lane bits 0..2)
    #pragma unroll
    for (int r = 0; r < 25; ++r) {
        acc0[r] += __shfl_xor(acc0[r], 1, 64);
        acc0[r] += __shfl_xor(acc0[r], 2, 64);
        acc0[r] += __shfl_xor(acc0[r], 4, 64);
        acc1[r] += __shfl_xor(acc1[r], 1, 64);
        acc1[r] += __shfl_xor(acc1[r], 2, 64);
        acc1[r] += __shfl_xor(acc1[r], 4, 64);
    }
    __syncthreads();                                     // all waves done reading W
    if (q == 0) {
        #pragma unroll
        for (int r = 0; r < 25; ++r) {
            ldsW[r * 64 + w * 8 + j]      = acc0[r];     // output tile [25][64]
            ldsW[r * 64 + 32 + w * 8 + j] = acc1[r];
        }
    }
    __syncthreads();
    for (int oi = tid; oi < 1600; oi += 256) {           // coalesced atomic adds
        int r = oi >> 6, cc = oi & 63;
        atomicAdd(&fe[((size_t)(r * B_ + b)) * D_ + 384 + ct * 64 + cc], ldsW[oi]);
    }
}

// ---------------- K3: G[i][b][j] = fe[i][b][:] @ W1 + b1 ; wave per (i,b,j-half) ----------------
__global__ __launch_bounds__(256) void mlp_pre_kernel(const float* __restrict__ fe,
        const float* __restrict__ W1T, const float* __restrict__ b1_0,
        const float* __restrict__ b1s, float* __restrict__ G) {
    int lane = threadIdx.x & 63;
    int trip = blockIdx.x * 4 + (threadIdx.x >> 6);      // 0..1599 = (i,b,jh)
    int jh = trip & 1;
    int pair = trip >> 1;
    int i = pair >> 5, b = pair & 31;
    const float4* f4p = (const float4*)(fe + (size_t)(i * B_ + b) * D_);
    float4 f0 = f4p[lane], f1 = f4p[lane + 64], f2 = f4p[lane + 128];
    int j0 = jh * 20;
    #pragma unroll 2
    for (int j = j0; j < j0 + 20; ++j) {
        const float4* w4p = (const float4*)(W1T + ((size_t)i * HID_ + j) * D_);
        float4 w0 = w4p[lane], w1 = w4p[lane + 64], w2 = w4p[lane + 128];
        float s = f0.x*w0.x + f0.y*w0.y + f0.z*w0.z + f0.w*w0.w
                + f1.x*w1.x + f1.y*w1.y + f1.z*w1.z + f1.w*w1.w
                + f2.x*w2.x + f2.y*w2.y + f2.z*w2.z + f2.w*w2.w;
        #pragma unroll
        for (int m = 32; m >= 1; m >>= 1) s += __shfl_xor(s, m, 64);
        if (lane == 0) {
            float bias = (i == 0) ? b1_0[j] : b1s[(i - 1) * HID_ + j];
            G[(size_t)(i * B_ + b) * HID_ + j] = s + bias;
        }
    }
}

// ---------------- K4: sequential heads, register-resident, wave-synchronous ----------------
__global__ __launch_bounds__(64) void mlp_seq_kernel(const float* __restrict__ G,
        const float* __restrict__ W1s, const float* __restrict__ W2_0,
        const float* __restrict__ b2_0, const float* __restrict__ W2s,
        const float* __restrict__ b2s, float* __restrict__ out) {
    int lane = threadIdx.x;
    int j2 = lane & 31, b = blockIdx.x * 2 + (lane >> 5);
    bool hi = (j2 < 8);
    float g1[25], g2[25], wl1[25], wl2[25], w2a[25], w2b[25], bsc[25];
    #pragma unroll
    for (int i = 0; i < 25; ++i) {
        g1[i] = G[(size_t)(i * B_ + b) * HID_ + j2];
        g2[i] = hi ? G[(size_t)(i * B_ + b) * HID_ + 32 + j2] : 0.f;
    }
    wl1[0] = 0.f; wl2[0] = 0.f;
    w2a[0] = W2_0[j2]; w2b[0] = hi ? W2_0[32 + j2] : 0.f; bsc[0] = b2_0[0];
    #pragma unroll
    for (int i = 1; i < 25; ++i) {
        size_t base = ((size_t)(i - 1) * 769 + 768) * HID_;   // recurrent row of W1
        wl1[i] = W1s[base + j2];
        wl2[i] = hi ? W1s[base + 32 + j2] : 0.f;
        w2a[i] = W2s[(i - 1) * HID_ + j2];
        w2b[i] = hi ? W2s[(i - 1) * HID_ + 32 + j2] : 0.f;
        bsc[i] = b2s[i - 1];
    }
    float op = 0.f;
    #pragma unroll
    for (int i = 0; i < 25; ++i) {
        float x1 = g1[i] + op * wl1[i];
        float x2 = g2[i] + op * wl2[i];
        float p = gelu_exact(x1) * w2a[i] + gelu_exact(x2) * w2b[i];
        #pragma unroll
        for (int m = 16; m >= 1; m >>= 1) p += __shfl_xor(p, m, 64);   // stays within 32-lane group
        float o = p + bsc[i];
        op = o;
        if (j2 == 0) out[b * 25 + i] = fminf(fmaxf(o, 0.f), 3.14159265358979323846f);
    }
}

extern "C" void kernel_launch(void* const* d_in, const int* in_sizes, int n_in,
                              void* d_out, int out_size, void* d_ws, size_t ws_size,
                              hipStream_t stream) {
    const float* polar = (const float*)d_in[0];
    const float* cart  = (const float*)d_in[1];
    const float* grid  = (const float*)d_in[2];
    const float* W1_0  = (const float*)d_in[3];
    const float* b1_0  = (const float*)d_in[4];
    const float* W2_0  = (const float*)d_in[5];
    const float* b2_0  = (const float*)d_in[6];
    const float* W1s   = (const float*)d_in[7];
    const float* b1s   = (const float*)d_in[8];
    const float* W2s   = (const float*)d_in[9];
    const float* b2s   = (const float*)d_in[10];
    float* out = (float*)d_out;

    // ws layout (floats): bins[800*4096] | fe | G | W1T
    float* bins = (float*)d_ws;
    float* fe   = bins + (size_t)B_ * RHO_ * PIX_;
    float* G    = fe + (size_t)FE_N;
    float* W1T  = G + (size_t)RHO_ * B_ * HID_;

    front_kernel<<<POLARBLK + B_ * RHO_ + 25 + 50, 256, 0, stream>>>(polar, grid, W1_0, W1s, bins, W1T, fe);
    cart_kernel<<<1536, 256, 0, stream>>>(cart, bins, fe);
    mlp_pre_kernel<<<(RHO_ * B_ * 2) / 4, 256, 0, stream>>>(fe, W1T, b1_0, b1s, G);
    mlp_seq_kernel<<<B_ / 2, 64, 0, stream>>>(G, W1s, W2_0, b2_0, W2s, b2s, out);
}